// Round 8
// baseline (51.363 us; speedup 1.0000x reference)
//
#include <hip/hip_runtime.h>

#define NFEAT 40
#define EMB   64
#define ATT   32
#define NPAIR 780
#define XH_S  72      // fp16 x LDS stride (elems) -> 144 B row stride

typedef __attribute__((ext_vector_type(8))) _Float16 f16x8;
typedef __attribute__((ext_vector_type(4))) _Float16 f16x4;
typedef __attribute__((ext_vector_type(4))) float    f32x4;

template <int CTRL>
__device__ __forceinline__ float dpp_add_f(float v) {
  int t = __builtin_amdgcn_update_dpp(0, __float_as_int(v), CTRL, 0xF, 0xF, true);
  return v + __int_as_float(t);
}
__device__ __forceinline__ float rowsum16(float v) {
  v = dpp_add_f<0x128>(v);
  v = dpp_add_f<0x124>(v);
  v = dpp_add_f<0x122>(v);
  v = dpp_add_f<0x121>(v);
  return v;
}

__device__ __forceinline__ int pair_off(int i) { return 39 * i - (i * (i - 1)) / 2; }

extern "C" __global__ __launch_bounds__(512)
void afm_kernel(const float* __restrict__ xg, const float* __restrict__ Wg,
                const float* __restrict__ bg, const float* __restrict__ hg,
                const float* __restrict__ pg, float* __restrict__ outg) {
  __shared__ __align__(16) _Float16 xh[NFEAT * XH_S];   // 5760 B
  __shared__ float red[8][2];

  const int tid  = threadIdx.x;
  const int lane = tid & 63, wid = tid >> 6;            // 8 waves
  const int l15  = lane & 15, hk = lane >> 4;
  const int bb   = blockIdx.x;

  // ---- W fragments (A operand; D = [att][pair]) ----
  f16x8 wf0[2], wf1[2], wf2[2];
#pragma unroll
  for (int kk = 0; kk < 2; kk++) {
    f16x8 r0, r1, r2;
#pragma unroll
    for (int t = 0; t < 8; t++) {
      int krow = kk * 32 + hk * 8 + t;
      r0[t] = (_Float16)Wg[krow * ATT + l15];
      r1[t] = (_Float16)Wg[krow * ATT + 16 + l15];
      _Float16 pv = (_Float16)pg[krow];
      r2[t] = (l15 == 0) ? pv : (_Float16)0.f;   // A row 0 = p vector
    }
    wf0[kk] = r0; wf1[kk] = r1; wf2[kk] = r2;
  }
  const float4 b0 = *(const float4*)&bg[hk * 4];
  const float4 b1 = *(const float4*)&bg[16 + hk * 4];
  const float4 h0 = *(const float4*)&hg[hk * 4];
  const float4 h1 = *(const float4*)&hg[16 + hk * 4];

  // ---- per-wave pair LDS byte offsets in registers (7 tiles max/wave) ----
  unsigned pij[7];
#pragma unroll
  for (int t = 0; t < 7; t++) {
    int p = (wid + 8 * t) * 16 + l15;
    int i = 0, j = 0;
    if (p < NPAIR) {
      i = (int)((79.0f - sqrtf(6241.0f - 8.0f * (float)p)) * 0.5f);
      if (i < 0) i = 0;
      while (pair_off(i + 1) <= p) ++i;
      while (pair_off(i) > p) --i;
      j = i + 1 + (p - pair_off(i));
    }
    pij[t] = (unsigned)(i * 144 + hk * 16) | ((unsigned)(j * 144 + hk * 16) << 16);
  }

  // ---- stage x -> fp16 LDS ----
  const float4* xsrc = (const float4*)(xg + (size_t)bb * (NFEAT * EMB));
  for (int f = tid; f < NFEAT * EMB / 4; f += 512) {
    float4 v = xsrc[f];
    int row = f >> 4, c = (f & 15) * 4;
    f16x4 h4 = {(_Float16)v.x, (_Float16)v.y, (_Float16)v.z, (_Float16)v.w};
    *(f16x4*)&xh[row * XH_S + c] = h4;
  }
  __syncthreads();

  const f32x4 kz = {0.f, 0.f, 0.f, 0.f};

  float sum_e = 0.f, sum_es = 0.f;
#pragma unroll
  for (int t = 0; t < 7; t++) {
    if (t < 6 || wid == 0) {                // tile m = wid + 8t < 49
      const unsigned offi = pij[t] & 0xFFFFu;
      const unsigned offj = pij[t] >> 16;
      const f16x8 xi0 = *(const f16x8*)((const char*)xh + offi);
      const f16x8 xj0 = *(const f16x8*)((const char*)xh + offj);
      const f16x8 xi1 = *(const f16x8*)((const char*)xh + offi + 64);
      const f16x8 xj1 = *(const f16x8*)((const char*)xh + offj + 64);
      f16x8 af0 = xi0 * xj0;
      f16x8 af1 = xi1 * xj1;
      f32x4 acc0 = __builtin_amdgcn_mfma_f32_16x16x32_f16(wf0[0], af0, kz, 0, 0, 0);
      f32x4 acc1 = __builtin_amdgcn_mfma_f32_16x16x32_f16(wf1[0], af0, kz, 0, 0, 0);
      f32x4 acc2 = __builtin_amdgcn_mfma_f32_16x16x32_f16(wf2[0], af0, kz, 0, 0, 0);
      acc0 = __builtin_amdgcn_mfma_f32_16x16x32_f16(wf0[1], af1, acc0, 0, 0, 0);
      acc1 = __builtin_amdgcn_mfma_f32_16x16x32_f16(wf1[1], af1, acc1, 0, 0, 0);
      acc2 = __builtin_amdgcn_mfma_f32_16x16x32_f16(wf2[1], af1, acc2, 0, 0, 0);
      float va = fmaf(fmaxf(acc0[0] + b0.x, 0.f), h0.x,
                 fmaf(fmaxf(acc0[1] + b0.y, 0.f), h0.y,
                 fmaf(fmaxf(acc0[2] + b0.z, 0.f), h0.z,
                      fmaxf(acc0[3] + b0.w, 0.f) * h0.w)));
      float vb = fmaf(fmaxf(acc1[0] + b1.x, 0.f), h1.x,
                 fmaf(fmaxf(acc1[1] + b1.y, 0.f), h1.y,
                 fmaf(fmaxf(acc1[2] + b1.z, 0.f), h1.z,
                      fmaxf(acc1[3] + b1.w, 0.f) * h1.w)));
      float v = va + vb;
      v += __shfl_xor(v, 16, 64);
      v += __shfl_xor(v, 32, 64);
      float e = __expf(v);
      if (t == 6) e = (l15 < 12) ? e : 0.f;  // tile 48: pairs 780..783 pad
      sum_e += e;                             // counted 4x (hk groups)
      sum_es = fmaf(e, acc2[0], sum_es);      // acc2[0]==0 unless hk==0
    }
  }

  // wave reduce then block reduce
  sum_e = rowsum16(sum_e);
  sum_e += __shfl_xor(sum_e, 16, 64);
  sum_e += __shfl_xor(sum_e, 32, 64);
  sum_es = rowsum16(sum_es);
  sum_es += __shfl_xor(sum_es, 16, 64);
  sum_es += __shfl_xor(sum_es, 32, 64);
  if (lane == 0) { red[wid][0] = sum_e; red[wid][1] = sum_es; }
  __syncthreads();
  if (tid == 0) {
    float Z = 0.f, S = 0.f;
#pragma unroll
    for (int w = 0; w < 8; w++) { Z += red[w][0]; S += red[w][1]; }
    outg[bb] = S / (Z * 0.25f);
  }
}

extern "C" void kernel_launch(void* const* d_in, const int* in_sizes, int n_in,
                              void* d_out, int out_size, void* d_ws, size_t ws_size,
                              hipStream_t stream) {
  const float* xg = (const float*)d_in[0];
  const float* Wg = (const float*)d_in[1];
  const float* bg = (const float*)d_in[2];
  const float* hg = (const float*)d_in[3];
  const float* pg = (const float*)d_in[4];
  float* outg = (float*)d_out;
  const int Bn = in_sizes[0] / (NFEAT * EMB);
  afm_kernel<<<dim3(Bn), dim3(512), 0, stream>>>(xg, Wg, bg, hg, pg, outg);
}

// Round 9
// 44.323 us; speedup vs baseline: 1.1588x; 1.1588x over previous
//
#include <hip/hip_runtime.h>

#define NFEAT 40
#define EMB   64
#define ATT   32
#define NPAIR 780
#define XH_S  72      // fp16 x LDS stride (elems) -> 144 B row stride

typedef __attribute__((ext_vector_type(8))) _Float16 f16x8;
typedef __attribute__((ext_vector_type(4))) _Float16 f16x4;
typedef __attribute__((ext_vector_type(4))) float    f32x4;

template <int CTRL>
__device__ __forceinline__ float dpp_add_f(float v) {
  int t = __builtin_amdgcn_update_dpp(0, __float_as_int(v), CTRL, 0xF, 0xF, true);
  return v + __int_as_float(t);
}
__device__ __forceinline__ float rowsum16(float v) {
  v = dpp_add_f<0x128>(v);
  v = dpp_add_f<0x124>(v);
  v = dpp_add_f<0x122>(v);
  v = dpp_add_f<0x121>(v);
  return v;
}

__device__ __forceinline__ int pair_off(int i) { return 39 * i - (i * (i - 1)) / 2; }

extern "C" __global__ __launch_bounds__(256)
void afm_kernel(const float* __restrict__ xg, const float* __restrict__ Wg,
                const float* __restrict__ bg, const float* __restrict__ hg,
                const float* __restrict__ pg, float* __restrict__ outg, int nbatch) {
  __shared__ __align__(16) _Float16 xh[NFEAT * XH_S];   // 5760 B
  __shared__ float red[4][2];

  const int tid  = threadIdx.x;
  const int lane = tid & 63, wid = tid >> 6;
  const int l15  = lane & 15, hk = lane >> 4;

  // ---- W fragments (A operand; D = [att][pair]); wf2 row0 = p ----
  f16x8 wf0[2], wf1[2], wf2[2];
#pragma unroll
  for (int kk = 0; kk < 2; kk++) {
    f16x8 r0, r1, r2;
#pragma unroll
    for (int t = 0; t < 8; t++) {
      int krow = kk * 32 + hk * 8 + t;
      r0[t] = (_Float16)Wg[krow * ATT + l15];
      r1[t] = (_Float16)Wg[krow * ATT + 16 + l15];
      _Float16 pv = (_Float16)pg[krow];
      r2[t] = (l15 == 0) ? pv : (_Float16)0.f;
    }
    wf0[kk] = r0; wf1[kk] = r1; wf2[kk] = r2;
  }
  // bias as MFMA C-in: reg r of acc0 <-> att hk*4+r, acc1 <-> 16+hk*4+r
  const float4 b0 = *(const float4*)&bg[hk * 4];
  const float4 b1 = *(const float4*)&bg[16 + hk * 4];
  const f32x4 cb0 = {b0.x, b0.y, b0.z, b0.w};
  const f32x4 cb1 = {b1.x, b1.y, b1.z, b1.w};
  // h-row A-fragment for the logit MFMA: element t <-> k=hk*8+t holds
  // h[A(hk,t)], A = t<4 ? hk*4+t : 16+hk*4+(t-4); only l15==0 (row 0) nonzero
  f16x8 hA;
#pragma unroll
  for (int t = 0; t < 8; t++) {
    int att = (t < 4) ? (hk * 4 + t) : (16 + hk * 4 + (t - 4));
    hA[t] = (l15 == 0) ? (_Float16)hg[att] : (_Float16)0.f;
  }

  // ---- per-wave pair LDS byte offsets in registers ----
  unsigned pij[13];
#pragma unroll
  for (int t = 0; t < 13; t++) {
    int p = (wid + 4 * t) * 16 + l15;
    int i = 0, j = 0;
    if (p < NPAIR) {
      i = (int)((79.0f - sqrtf(6241.0f - 8.0f * (float)p)) * 0.5f);
      if (i < 0) i = 0;
      while (pair_off(i + 1) <= p) ++i;
      while (pair_off(i) > p) --i;
      j = i + 1 + (p - pair_off(i));
    }
    pij[t] = (unsigned)(i * 144 + hk * 16) | ((unsigned)(j * 144 + hk * 16) << 16);
  }

  const f32x4 kz = {0.f, 0.f, 0.f, 0.f};

  // ---- 2 batches per block ----
  for (int it = 0; it < 2; it++) {
    const int bb = blockIdx.x * 2 + it;
    if (bb >= nbatch) break;

    const float4* xsrc = (const float4*)(xg + (size_t)bb * (NFEAT * EMB));
    for (int f = tid; f < NFEAT * EMB / 4; f += 256) {
      float4 v = xsrc[f];
      int row = f >> 4, c = (f & 15) * 4;
      f16x4 h4 = {(_Float16)v.x, (_Float16)v.y, (_Float16)v.z, (_Float16)v.w};
      *(f16x4*)&xh[row * XH_S + c] = h4;
    }
    __syncthreads();

    float sum_e = 0.f, sum_es = 0.f;
#pragma unroll
    for (int t = 0; t < 13; t++) {
      if (t < 12 || wid == 0) {               // tile m = wid + 4t < 49
        const unsigned offi = pij[t] & 0xFFFFu;
        const unsigned offj = pij[t] >> 16;
        const f16x8 xi0 = *(const f16x8*)((const char*)xh + offi);
        const f16x8 xj0 = *(const f16x8*)((const char*)xh + offj);
        const f16x8 xi1 = *(const f16x8*)((const char*)xh + offi + 64);
        const f16x8 xj1 = *(const f16x8*)((const char*)xh + offj + 64);
        f16x8 af0 = xi0 * xj0;
        f16x8 af1 = xi1 * xj1;
        f32x4 acc0 = __builtin_amdgcn_mfma_f32_16x16x32_f16(wf0[0], af0, cb0, 0, 0, 0);
        f32x4 acc1 = __builtin_amdgcn_mfma_f32_16x16x32_f16(wf1[0], af0, cb1, 0, 0, 0);
        f32x4 acc2 = __builtin_amdgcn_mfma_f32_16x16x32_f16(wf2[0], af0, kz, 0, 0, 0);
        acc0 = __builtin_amdgcn_mfma_f32_16x16x32_f16(wf0[1], af1, acc0, 0, 0, 0);
        acc1 = __builtin_amdgcn_mfma_f32_16x16x32_f16(wf1[1], af1, acc1, 0, 0, 0);
        acc2 = __builtin_amdgcn_mfma_f32_16x16x32_f16(wf2[1], af1, acc2, 0, 0, 0);
        // relu'd scores ARE a B-fragment (col=l15, k=hk*8+t); RNE casts
        f16x8 pb;
        pb[0] = (_Float16)fmaxf(acc0[0], 0.f);
        pb[1] = (_Float16)fmaxf(acc0[1], 0.f);
        pb[2] = (_Float16)fmaxf(acc0[2], 0.f);
        pb[3] = (_Float16)fmaxf(acc0[3], 0.f);
        pb[4] = (_Float16)fmaxf(acc1[0], 0.f);
        pb[5] = (_Float16)fmaxf(acc1[1], 0.f);
        pb[6] = (_Float16)fmaxf(acc1[2], 0.f);
        pb[7] = (_Float16)fmaxf(acc1[3], 0.f);
        f32x4 dlog = __builtin_amdgcn_mfma_f32_16x16x32_f16(hA, pb, kz, 0, 0, 0);
        float e = __expf(dlog[0]);              // logit at row0 -> hk==0, reg0
        e = (hk == 0) ? e : 0.f;
        if (t == 12) e = (l15 < 12) ? e : 0.f;  // pairs 780..783 pad
        sum_e += e;
        sum_es = fmaf(e, acc2[0], sum_es);      // s_p also at hk==0, reg0
      }
    }

    // lanes 0-15 hold this wave's partials; rowsum16 then block reduce
    sum_e  = rowsum16(sum_e);
    sum_es = rowsum16(sum_es);
    if (lane == 0) { red[wid][0] = sum_e; red[wid][1] = sum_es; }
    __syncthreads();
    if (tid == 0) {
      float Z = red[0][0] + red[1][0] + red[2][0] + red[3][0];
      float S = red[0][1] + red[1][1] + red[2][1] + red[3][1];
      outg[bb] = S / Z;
    }
  }
}

extern "C" void kernel_launch(void* const* d_in, const int* in_sizes, int n_in,
                              void* d_out, int out_size, void* d_ws, size_t ws_size,
                              hipStream_t stream) {
  const float* xg = (const float*)d_in[0];
  const float* Wg = (const float*)d_in[1];
  const float* bg = (const float*)d_in[2];
  const float* hg = (const float*)d_in[3];
  const float* pg = (const float*)d_in[4];
  float* outg = (float*)d_out;
  const int Bn = in_sizes[0] / (NFEAT * EMB);
  const int nblk = (Bn + 1) / 2;
  afm_kernel<<<dim3(nblk), dim3(256), 0, stream>>>(xg, Wg, bg, hg, pg, outg, Bn);
}

// Round 10
// 40.347 us; speedup vs baseline: 1.2730x; 1.0985x over previous
//
#include <hip/hip_runtime.h>

#define NFEAT 40
#define EMB   64
#define ATT   32
#define NPAIR 780
#define NTILE 49      // 49 tiles x 16 pairs = 784 (padded)
#define XH_S  72      // fp16 x LDS stride (elems) -> 144 B row stride

typedef __attribute__((ext_vector_type(8))) _Float16 f16x8;
typedef __attribute__((ext_vector_type(4))) _Float16 f16x4;
typedef __attribute__((ext_vector_type(4))) float    f32x4;

template <int CTRL>
__device__ __forceinline__ float dpp_add_f(float v) {
  int t = __builtin_amdgcn_update_dpp(0, __float_as_int(v), CTRL, 0xF, 0xF, true);
  return v + __int_as_float(t);
}
__device__ __forceinline__ float rowsum16(float v) {
  v = dpp_add_f<0x128>(v);
  v = dpp_add_f<0x124>(v);
  v = dpp_add_f<0x122>(v);
  v = dpp_add_f<0x121>(v);
  return v;
}

__device__ __forceinline__ int pair_off(int i) { return 39 * i - (i * (i - 1)) / 2; }

extern "C" __global__ __launch_bounds__(64)
void afm_kernel(const float* __restrict__ xg, const float* __restrict__ Wg,
                const float* __restrict__ bg, const float* __restrict__ hg,
                const float* __restrict__ pg, float* __restrict__ outg, int nbatch) {
  __shared__ __align__(16) _Float16 xh[NFEAT * XH_S];   // 5760 B
  __shared__ unsigned prt[NTILE * 16];                  // 3136 B

  const int lane = threadIdx.x;        // one wave per block
  const int l15  = lane & 15, hk = lane >> 4;
  const unsigned hkoff = hk * 16;

  // ---- pair table -> LDS (once per block, 13 iters on one wave) ----
  for (int p = lane; p < NTILE * 16; p += 64) {
    int i = 0, j = 0;
    if (p < NPAIR) {
      i = (int)((79.0f - sqrtf(6241.0f - 8.0f * (float)p)) * 0.5f);
      if (i < 0) i = 0;
      while (pair_off(i + 1) <= p) ++i;
      while (pair_off(i) > p) --i;
      j = i + 1 + (p - pair_off(i));
    }
    prt[p] = (unsigned)(i * 144) | ((unsigned)(j * 144) << 16);
  }

  // ---- W fragments (A operand; D = [att][pair]); wf2 row0 = p ----
  f16x8 wf0[2], wf1[2], wf2[2];
#pragma unroll
  for (int kk = 0; kk < 2; kk++) {
    f16x8 r0, r1, r2;
#pragma unroll
    for (int t = 0; t < 8; t++) {
      int krow = kk * 32 + hk * 8 + t;
      r0[t] = (_Float16)Wg[krow * ATT + l15];
      r1[t] = (_Float16)Wg[krow * ATT + 16 + l15];
      _Float16 pv = (_Float16)pg[krow];
      r2[t] = (l15 == 0) ? pv : (_Float16)0.f;
    }
    wf0[kk] = r0; wf1[kk] = r1; wf2[kk] = r2;
  }
  // bias as MFMA C-in: reg r of acc0 <-> att hk*4+r, acc1 <-> 16+hk*4+r
  const float4 b0 = *(const float4*)&bg[hk * 4];
  const float4 b1 = *(const float4*)&bg[16 + hk * 4];
  const f32x4 cb0 = {b0.x, b0.y, b0.z, b0.w};
  const f32x4 cb1 = {b1.x, b1.y, b1.z, b1.w};
  const float4 h0 = *(const float4*)&hg[hk * 4];
  const float4 h1 = *(const float4*)&hg[16 + hk * 4];

  const f32x4 kz = {0.f, 0.f, 0.f, 0.f};

  // ---- 2 batches per (single-wave) block ----
  for (int it = 0; it < 2; it++) {
    const int bb = blockIdx.x * 2 + it;
    if (bb >= nbatch) break;

    // stage x -> fp16 LDS (10 iters, 64 lanes)
    const float4* xsrc = (const float4*)(xg + (size_t)bb * (NFEAT * EMB));
#pragma unroll
    for (int f = lane; f < NFEAT * EMB / 4; f += 64) {
      float4 v = xsrc[f];
      int row = f >> 4, c = (f & 15) * 4;
      f16x4 h4 = {(_Float16)v.x, (_Float16)v.y, (_Float16)v.z, (_Float16)v.w};
      *(f16x4*)&xh[row * XH_S + c] = h4;
    }
    __syncthreads();   // trivial for 1 wave; orders LDS write->read

    float sum_e = 0.f, sum_es = 0.f;
#pragma unroll 4
    for (int t = 0; t < NTILE; t++) {
      const unsigned pij = prt[t * 16 + l15];
      const unsigned offi = (pij & 0xFFFFu) + hkoff;
      const unsigned offj = (pij >> 16) + hkoff;
      const f16x8 xi0 = *(const f16x8*)((const char*)xh + offi);
      const f16x8 xj0 = *(const f16x8*)((const char*)xh + offj);
      const f16x8 xi1 = *(const f16x8*)((const char*)xh + offi + 64);
      const f16x8 xj1 = *(const f16x8*)((const char*)xh + offj + 64);
      f16x8 af0 = xi0 * xj0;
      f16x8 af1 = xi1 * xj1;
      f32x4 acc0 = __builtin_amdgcn_mfma_f32_16x16x32_f16(wf0[0], af0, cb0, 0, 0, 0);
      f32x4 acc1 = __builtin_amdgcn_mfma_f32_16x16x32_f16(wf1[0], af0, cb1, 0, 0, 0);
      f32x4 acc2 = __builtin_amdgcn_mfma_f32_16x16x32_f16(wf2[0], af0, kz, 0, 0, 0);
      acc0 = __builtin_amdgcn_mfma_f32_16x16x32_f16(wf0[1], af1, acc0, 0, 0, 0);
      acc1 = __builtin_amdgcn_mfma_f32_16x16x32_f16(wf1[1], af1, acc1, 0, 0, 0);
      acc2 = __builtin_amdgcn_mfma_f32_16x16x32_f16(wf2[1], af1, acc2, 0, 0, 0);
      float va = fmaf(fmaxf(acc0[0], 0.f), h0.x,
                 fmaf(fmaxf(acc0[1], 0.f), h0.y,
                 fmaf(fmaxf(acc0[2], 0.f), h0.z,
                      fmaxf(acc0[3], 0.f) * h0.w)));
      float vb = fmaf(fmaxf(acc1[0], 0.f), h1.x,
                 fmaf(fmaxf(acc1[1], 0.f), h1.y,
                 fmaf(fmaxf(acc1[2], 0.f), h1.z,
                      fmaxf(acc1[3], 0.f) * h1.w)));
      float v = va + vb;
      v += __shfl_xor(v, 16, 64);
      v += __shfl_xor(v, 32, 64);
      float e = (t * 16 + l15 < NPAIR) ? __expf(v) : 0.f;
      sum_e += e;                          // identical across hk rows
      sum_es = fmaf(e, acc2[0], sum_es);   // acc2[0]==0 unless hk==0
    }

    // final: one in-row reduction; row 0 (hk==0) holds the true sums
    sum_e  = rowsum16(sum_e);
    sum_es = rowsum16(sum_es);
    if (lane == 0) outg[bb] = sum_es / sum_e;
    __syncthreads();   // protect xh before next batch's staging
  }
}

extern "C" void kernel_launch(void* const* d_in, const int* in_sizes, int n_in,
                              void* d_out, int out_size, void* d_ws, size_t ws_size,
                              hipStream_t stream) {
  const float* xg = (const float*)d_in[0];
  const float* Wg = (const float*)d_in[1];
  const float* bg = (const float*)d_in[2];
  const float* hg = (const float*)d_in[3];
  const float* pg = (const float*)d_in[4];
  float* outg = (float*)d_out;
  const int Bn = in_sizes[0] / (NFEAT * EMB);
  const int nblk = (Bn + 1) / 2;
  afm_kernel<<<dim3(nblk), dim3(64), 0, stream>>>(xg, Wg, bg, hg, pg, outg, Bn);
}

// Round 11
// 35.936 us; speedup vs baseline: 1.4293x; 1.1227x over previous
//
#include <hip/hip_runtime.h>

#define NFEAT 40
#define EMB   64
#define ATT   32
#define NPAIR 780
#define NTILE 49      // 49 tiles x 16 pairs = 784 (padded)
#define XH_S  72      // fp16 x LDS stride (elems) -> 144 B row stride
#define XREG  (NFEAT * XH_S)   // 2880 elems = 5760 B per wave region

typedef __attribute__((ext_vector_type(8))) _Float16 f16x8;
typedef __attribute__((ext_vector_type(4))) _Float16 f16x4;
typedef __attribute__((ext_vector_type(4))) float    f32x4;

template <int CTRL>
__device__ __forceinline__ float dpp_add_f(float v) {
  int t = __builtin_amdgcn_update_dpp(0, __float_as_int(v), CTRL, 0xF, 0xF, true);
  return v + __int_as_float(t);
}
__device__ __forceinline__ float rowsum16(float v) {
  v = dpp_add_f<0x128>(v);
  v = dpp_add_f<0x124>(v);
  v = dpp_add_f<0x122>(v);
  v = dpp_add_f<0x121>(v);
  return v;
}

__device__ __forceinline__ int pair_off(int i) { return 39 * i - (i * (i - 1)) / 2; }

extern "C" __global__ __launch_bounds__(256)
void afm_kernel(const float* __restrict__ xg, const float* __restrict__ Wg,
                const float* __restrict__ bg, const float* __restrict__ hg,
                const float* __restrict__ pg, float* __restrict__ outg, int nbatch) {
  __shared__ __align__(16) _Float16 xh[4 * XREG];       // 23040 B (4 wave regions)
  __shared__ unsigned prt[NTILE * 16];                  // 3136 B

  const int tid  = threadIdx.x;
  const int lane = tid & 63, wid = tid >> 6;
  const int l15  = lane & 15, hk = lane >> 4;
  const int bb   = blockIdx.x * 4 + wid;                // one batch per wave

  // ---- pair table -> LDS (block-cooperative, once) ----
  for (int p = tid; p < NTILE * 16; p += 256) {
    int i = 0, j = 0;
    if (p < NPAIR) {
      i = (int)((79.0f - sqrtf(6241.0f - 8.0f * (float)p)) * 0.5f);
      if (i < 0) i = 0;
      while (pair_off(i + 1) <= p) ++i;
      while (pair_off(i) > p) --i;
      j = i + 1 + (p - pair_off(i));
    }
    prt[p] = (unsigned)(i * 144) | ((unsigned)(j * 144) << 16);
  }

  // ---- W fragments (A operand; D = [att][pair]); wf2 row0 = p ----
  f16x8 wf0[2], wf1[2], wf2[2];
#pragma unroll
  for (int kk = 0; kk < 2; kk++) {
    f16x8 r0, r1, r2;
#pragma unroll
    for (int t = 0; t < 8; t++) {
      int krow = kk * 32 + hk * 8 + t;
      r0[t] = (_Float16)Wg[krow * ATT + l15];
      r1[t] = (_Float16)Wg[krow * ATT + 16 + l15];
      _Float16 pv = (_Float16)pg[krow];
      r2[t] = (l15 == 0) ? pv : (_Float16)0.f;
    }
    wf0[kk] = r0; wf1[kk] = r1; wf2[kk] = r2;
  }
  const float4 b0 = *(const float4*)&bg[hk * 4];
  const float4 b1 = *(const float4*)&bg[16 + hk * 4];
  const f32x4 cb0 = {b0.x, b0.y, b0.z, b0.w};
  const f32x4 cb1 = {b1.x, b1.y, b1.z, b1.w};
  const float4 h0 = *(const float4*)&hg[hk * 4];
  const float4 h1 = *(const float4*)&hg[16 + hk * 4];
  const f32x4 kz = {0.f, 0.f, 0.f, 0.f};

  // ---- stage own batch -> own LDS region (10 iters/wave) ----
  const bool live = bb < nbatch;
  _Float16* xw = &xh[wid * XREG];
  if (live) {
    const float4* xsrc = (const float4*)(xg + (size_t)bb * (NFEAT * EMB));
#pragma unroll
    for (int f = lane; f < NFEAT * EMB / 4; f += 64) {
      float4 v = xsrc[f];
      int row = f >> 4, c = (f & 15) * 4;
      f16x4 h4 = {(_Float16)v.x, (_Float16)v.y, (_Float16)v.z, (_Float16)v.w};
      *(f16x4*)&xw[row * XH_S + c] = h4;
    }
  }
  __syncthreads();   // prt visible to all; staging ordered (only barrier)

  if (!live) return;
  const unsigned wh = (unsigned)(wid * (XREG * 2) + hk * 16);  // byte base

  float sum_e = 0.f, sum_es = 0.f;
#pragma unroll 7
  for (int t = 0; t < NTILE - 1; t++) {
    const unsigned pij = prt[t * 16 + l15];
    const unsigned offi = (pij & 0xFFFFu) + wh;
    const unsigned offj = (pij >> 16) + wh;
    const f16x8 xi0 = *(const f16x8*)((const char*)xh + offi);
    const f16x8 xj0 = *(const f16x8*)((const char*)xh + offj);
    const f16x8 xi1 = *(const f16x8*)((const char*)xh + offi + 64);
    const f16x8 xj1 = *(const f16x8*)((const char*)xh + offj + 64);
    f16x8 af0 = xi0 * xj0;
    f16x8 af1 = xi1 * xj1;
    f32x4 acc0 = __builtin_amdgcn_mfma_f32_16x16x32_f16(wf0[0], af0, cb0, 0, 0, 0);
    f32x4 acc1 = __builtin_amdgcn_mfma_f32_16x16x32_f16(wf1[0], af0, cb1, 0, 0, 0);
    f32x4 acc2 = __builtin_amdgcn_mfma_f32_16x16x32_f16(wf2[0], af0, kz, 0, 0, 0);
    acc0 = __builtin_amdgcn_mfma_f32_16x16x32_f16(wf0[1], af1, acc0, 0, 0, 0);
    acc1 = __builtin_amdgcn_mfma_f32_16x16x32_f16(wf1[1], af1, acc1, 0, 0, 0);
    acc2 = __builtin_amdgcn_mfma_f32_16x16x32_f16(wf2[1], af1, acc2, 0, 0, 0);
    float va = fmaf(fmaxf(acc0[0], 0.f), h0.x,
               fmaf(fmaxf(acc0[1], 0.f), h0.y,
               fmaf(fmaxf(acc0[2], 0.f), h0.z,
                    fmaxf(acc0[3], 0.f) * h0.w)));
    float vb = fmaf(fmaxf(acc1[0], 0.f), h1.x,
               fmaf(fmaxf(acc1[1], 0.f), h1.y,
               fmaf(fmaxf(acc1[2], 0.f), h1.z,
                    fmaxf(acc1[3], 0.f) * h1.w)));
    float v = va + vb;
    v += __shfl_xor(v, 16, 64);
    v += __shfl_xor(v, 32, 64);
    float e = __expf(v);
    sum_e += e;                          // identical across hk rows
    sum_es = fmaf(e, acc2[0], sum_es);   // acc2[0]==0 unless hk==0
  }
  {  // tail tile 48: pairs 768..779 valid, 780..783 pad
    const int t = NTILE - 1;
    const unsigned pij = prt[t * 16 + l15];
    const unsigned offi = (pij & 0xFFFFu) + wh;
    const unsigned offj = (pij >> 16) + wh;
    const f16x8 xi0 = *(const f16x8*)((const char*)xh + offi);
    const f16x8 xj0 = *(const f16x8*)((const char*)xh + offj);
    const f16x8 xi1 = *(const f16x8*)((const char*)xh + offi + 64);
    const f16x8 xj1 = *(const f16x8*)((const char*)xh + offj + 64);
    f16x8 af0 = xi0 * xj0;
    f16x8 af1 = xi1 * xj1;
    f32x4 acc0 = __builtin_amdgcn_mfma_f32_16x16x32_f16(wf0[0], af0, cb0, 0, 0, 0);
    f32x4 acc1 = __builtin_amdgcn_mfma_f32_16x16x32_f16(wf1[0], af0, cb1, 0, 0, 0);
    f32x4 acc2 = __builtin_amdgcn_mfma_f32_16x16x32_f16(wf2[0], af0, kz, 0, 0, 0);
    acc0 = __builtin_amdgcn_mfma_f32_16x16x32_f16(wf0[1], af1, acc0, 0, 0, 0);
    acc1 = __builtin_amdgcn_mfma_f32_16x16x32_f16(wf1[1], af1, acc1, 0, 0, 0);
    acc2 = __builtin_amdgcn_mfma_f32_16x16x32_f16(wf2[1], af1, acc2, 0, 0, 0);
    float va = fmaf(fmaxf(acc0[0], 0.f), h0.x,
               fmaf(fmaxf(acc0[1], 0.f), h0.y,
               fmaf(fmaxf(acc0[2], 0.f), h0.z,
                    fmaxf(acc0[3], 0.f) * h0.w)));
    float vb = fmaf(fmaxf(acc1[0], 0.f), h1.x,
               fmaf(fmaxf(acc1[1], 0.f), h1.y,
               fmaf(fmaxf(acc1[2], 0.f), h1.z,
                    fmaxf(acc1[3], 0.f) * h1.w)));
    float v = va + vb;
    v += __shfl_xor(v, 16, 64);
    v += __shfl_xor(v, 32, 64);
    float e = (l15 < 12) ? __expf(v) : 0.f;
    sum_e += e;
    sum_es = fmaf(e, acc2[0], sum_es);
  }

  // one in-row reduction; row 0 (hk==0) lane 0 holds the true sums
  sum_e  = rowsum16(sum_e);
  sum_es = rowsum16(sum_es);
  if (lane == 0) outg[bb] = sum_es / sum_e;
}

extern "C" void kernel_launch(void* const* d_in, const int* in_sizes, int n_in,
                              void* d_out, int out_size, void* d_ws, size_t ws_size,
                              hipStream_t stream) {
  const float* xg = (const float*)d_in[0];
  const float* Wg = (const float*)d_in[1];
  const float* bg = (const float*)d_in[2];
  const float* hg = (const float*)d_in[3];
  const float* pg = (const float*)d_in[4];
  float* outg = (float*)d_out;
  const int Bn = in_sizes[0] / (NFEAT * EMB);
  const int nblk = (Bn + 3) / 4;
  afm_kernel<<<dim3(nblk), dim3(256), 0, stream>>>(xg, Wg, bg, hg, pg, outg, Bn);
}